// Round 7
// baseline (56.871 us; speedup 1.0000x reference)
//
#include <hip/hip_runtime.h>
#include <math.h>

#define BB 32
#define CC 256
#define HH 64
#define WW 64
#define RR 16
#define HWSZ (HH * WW)          // 4096
#define POS 205                 // max(1, round(0.8 * 256))

typedef float f32x4 __attribute__((ext_vector_type(4)));

// ---------------------------------------------------------------------------
// Kernel 1: fused copy + mean, 2 rows per block.
// Plain caching loads; NT stores (keeps out from evicting x in LLC — profile
// shows FETCH 67MB < 134MB across replays thanks to this).
// ---------------------------------------------------------------------------
__global__ void mean_copy_kernel(const float* __restrict__ x,
                                 float* __restrict__ out,
                                 float* __restrict__ y) {
    const int r0 = blockIdx.x * 2;                   // rows r0, r0+1
    const int t = threadIdx.x;                       // 0 .. 255
    const f32x4* x0 = (const f32x4*)(x + (size_t)r0 * HWSZ);
    f32x4* o0 = (f32x4*)(out + (size_t)r0 * HWSZ);

    f32x4 v0[4], v1[4];
#pragma unroll
    for (int i = 0; i < 4; ++i) v0[i] = x0[t + i * 256];
#pragma unroll
    for (int i = 0; i < 4; ++i) v1[i] = x0[1024 + t + i * 256];

    float s0 = 0.f, s1 = 0.f;
#pragma unroll
    for (int i = 0; i < 4; ++i) {
        __builtin_nontemporal_store(v0[i], &o0[t + i * 256]);
        s0 += v0[i].x + v0[i].y + v0[i].z + v0[i].w;
    }
#pragma unroll
    for (int i = 0; i < 4; ++i) {
        __builtin_nontemporal_store(v1[i], &o0[1024 + t + i * 256]);
        s1 += v1[i].x + v1[i].y + v1[i].z + v1[i].w;
    }

#pragma unroll
    for (int off = 32; off > 0; off >>= 1) {
        s0 += __shfl_down(s0, off, 64);
        s1 += __shfl_down(s1, off, 64);
    }
    __shared__ float red[8];
    const int wave = t >> 6;
    if ((t & 63) == 0) { red[wave] = s0; red[wave + 4] = s1; }
    __syncthreads();
    if (t == 0) {
        y[r0]     = (red[0] + red[1] + red[2] + red[3]) * (1.0f / (float)HWSZ);
        y[r0 + 1] = (red[4] + red[5] + red[6] + red[7]) * (1.0f / (float)HWSZ);
    }
}

// ---------------------------------------------------------------------------
// Kernel 2: fused SE + zero. 2048 blocks = 64 per batch. Each block
// REDUNDANTLY computes its batch's SE bottleneck + rank mask (y is 1 KB,
// W1/W2 17 KB — L2 broadcast), then zeroes its 4-channel share of the
// masked-off rows. No mask round-trip through global, one less launch.
//   h[r] = relu(sum_c y[c] * W1[r,c])
//   s[c] = sigmoid(sum_r h[r] * W2[c,r])
//   keep[c] = (#{j : s[j] < s[c]} <= POS-1)  ==  (s[c] <= sorted(s)[POS-1])
// ---------------------------------------------------------------------------
__global__ void se_zero_kernel(const float* __restrict__ y,
                               const float* __restrict__ W1,
                               const float* __restrict__ W2,
                               float* __restrict__ out) {
    const int b = blockIdx.x >> 6;                   // batch 0..31
    const int k = blockIdx.x & 63;                   // sub-block 0..63
    const int t = threadIdx.x;                       // 0 .. 255
    __shared__ float ys[CC];
    __shared__ float hs[RR];
    __shared__ float ss[CC];
    __shared__ int   keep[CC];

    ys[t] = y[b * CC + t];
    __syncthreads();

    {   // h[r]: r = t>>4 (0..15), 16-lane group splits the 256-dot
        const int r = t >> 4;
        const int p = t & 15;
        float acc = 0.f;
#pragma unroll
        for (int j = 0; j < 16; ++j)
            acc += ys[p * 16 + j] * W1[r * CC + p * 16 + j];
#pragma unroll
        for (int off = 8; off > 0; off >>= 1) acc += __shfl_xor(acc, off, 16);
        if (p == 0) hs[r] = fmaxf(acc, 0.f);
    }
    __syncthreads();

    float acc = 0.f;
#pragma unroll
    for (int r = 0; r < RR; ++r) acc += hs[r] * W2[t * RR + r];
    const float s = 1.0f / (1.0f + expf(-acc));
    ss[t] = s;
    __syncthreads();

    int cnt = 0;
    for (int j = 0; j < CC; ++j) cnt += (ss[j] < s) ? 1 : 0;
    keep[t] = (cnt <= POS - 1) ? 1 : 0;
    __syncthreads();

    // zero phase: this block owns channels {k, k+64, k+128, k+192} of batch b
    f32x4 z = {0.f, 0.f, 0.f, 0.f};
#pragma unroll
    for (int cc = 0; cc < 4; ++cc) {
        const int c = k + cc * 64;
        if (keep[c]) continue;
        f32x4* orow = (f32x4*)(out + ((size_t)b * CC + c) * HWSZ);
#pragma unroll
        for (int i = 0; i < 4; ++i)
            __builtin_nontemporal_store(z, &orow[t + i * 256]);
    }
}

extern "C" void kernel_launch(void* const* d_in, const int* in_sizes, int n_in,
                              void* d_out, int out_size, void* d_ws, size_t ws_size,
                              hipStream_t stream) {
    const float* x  = (const float*)d_in[0];
    const float* W1 = (const float*)d_in[1];
    const float* W2 = (const float*)d_in[2];
    float* out = (float*)d_out;

    float* y = (float*)d_ws;                    // B*C floats

    mean_copy_kernel<<<BB * CC / 2, 256, 0, stream>>>(x, out, y);
    se_zero_kernel<<<BB * 64, 256, 0, stream>>>(y, W1, W2, out);
}

// Round 8
// 53.493 us; speedup vs baseline: 1.0631x; 1.0631x over previous
//
#include <hip/hip_runtime.h>
#include <math.h>

#define BB 32
#define CC 256
#define HH 64
#define WW 64
#define RR 16
#define HWSZ (HH * WW)          // 4096
#define POS 205                 // max(1, round(0.8 * 256))

typedef float f32x4 __attribute__((ext_vector_type(4)));

// ---------------------------------------------------------------------------
// Kernel 1: fused copy + mean, 2 rows per block.
// Plain caching loads; NT stores (keeps out from evicting x in LLC — profile
// shows FETCH 67MB < 134MB across replays thanks to this).
// ---------------------------------------------------------------------------
__global__ void mean_copy_kernel(const float* __restrict__ x,
                                 float* __restrict__ out,
                                 float* __restrict__ y) {
    const int r0 = blockIdx.x * 2;                   // rows r0, r0+1
    const int t = threadIdx.x;                       // 0 .. 255
    const f32x4* x0 = (const f32x4*)(x + (size_t)r0 * HWSZ);
    f32x4* o0 = (f32x4*)(out + (size_t)r0 * HWSZ);

    f32x4 v0[4], v1[4];
#pragma unroll
    for (int i = 0; i < 4; ++i) v0[i] = x0[t + i * 256];
#pragma unroll
    for (int i = 0; i < 4; ++i) v1[i] = x0[1024 + t + i * 256];

    float s0 = 0.f, s1 = 0.f;
#pragma unroll
    for (int i = 0; i < 4; ++i) {
        __builtin_nontemporal_store(v0[i], &o0[t + i * 256]);
        s0 += v0[i].x + v0[i].y + v0[i].z + v0[i].w;
    }
#pragma unroll
    for (int i = 0; i < 4; ++i) {
        __builtin_nontemporal_store(v1[i], &o0[1024 + t + i * 256]);
        s1 += v1[i].x + v1[i].y + v1[i].z + v1[i].w;
    }

#pragma unroll
    for (int off = 32; off > 0; off >>= 1) {
        s0 += __shfl_down(s0, off, 64);
        s1 += __shfl_down(s1, off, 64);
    }
    __shared__ float red[8];
    const int wave = t >> 6;
    if ((t & 63) == 0) { red[wave] = s0; red[wave + 4] = s1; }
    __syncthreads();
    if (t == 0) {
        y[r0]     = (red[0] + red[1] + red[2] + red[3]) * (1.0f / (float)HWSZ);
        y[r0 + 1] = (red[4] + red[5] + red[6] + red[7]) * (1.0f / (float)HWSZ);
    }
}

// ---------------------------------------------------------------------------
// Kernel 2: fused SE + zero, 2048 blocks = 64 per batch. Each block
// recomputes its batch's SE bottleneck, but the rank-count is now
// ballot-based and only for the block's own 4 channels:
//   cnt(c) = #{j : s[j] < s[c]} via per-wave __ballot + popcount,
//   keep(c) = cnt <= POS-1   ==   s[c] <= sorted(s)[POS-1].
// Then zeroes its masked channels {k, k+64, k+128, k+192} of batch b.
// ---------------------------------------------------------------------------
__global__ void se_zero_kernel(const float* __restrict__ y,
                               const float* __restrict__ W1,
                               const float* __restrict__ W2,
                               float* __restrict__ out) {
    const int b = blockIdx.x >> 6;                   // batch 0..31
    const int k = blockIdx.x & 63;                   // sub-block 0..63
    const int t = threadIdx.x;                       // 0 .. 255
    __shared__ float ys[CC];
    __shared__ float hs[RR];
    __shared__ float ss[CC];
    __shared__ int cntred[4][4];                     // [cc][wave]
    __shared__ int keepb[4];

    ys[t] = y[b * CC + t];
    __syncthreads();

    {   // h[r]: r = t>>4 (0..15), 16-lane group splits the 256-dot
        const int r = t >> 4;
        const int p = t & 15;
        float acc = 0.f;
#pragma unroll
        for (int j = 0; j < 16; ++j)
            acc += ys[p * 16 + j] * W1[r * CC + p * 16 + j];
#pragma unroll
        for (int off = 8; off > 0; off >>= 1) acc += __shfl_xor(acc, off, 16);
        if (p == 0) hs[r] = fmaxf(acc, 0.f);
    }
    __syncthreads();

    float acc = 0.f;
#pragma unroll
    for (int r = 0; r < RR; ++r) acc += hs[r] * W2[t * RR + r];
    const float s = 1.0f / (1.0f + expf(-acc));
    ss[t] = s;
    __syncthreads();

    // rank counts for this block's 4 channels only, via wave ballots
    const int wave = t >> 6;
#pragma unroll
    for (int cc = 0; cc < 4; ++cc) {
        const float sc = ss[k + cc * 64];
        unsigned long long m = __ballot(s < sc);     // lanes j with s[j] < s[c]
        if ((t & 63) == 0) cntred[cc][wave] = __popcll(m);
    }
    __syncthreads();
    if (t < 4)
        keepb[t] = (cntred[t][0] + cntred[t][1] + cntred[t][2] + cntred[t][3]) <= POS - 1;
    __syncthreads();

    // zero phase: channels {k, k+64, k+128, k+192} of batch b
    f32x4 z = {0.f, 0.f, 0.f, 0.f};
#pragma unroll
    for (int cc = 0; cc < 4; ++cc) {
        if (keepb[cc]) continue;
        const int c = k + cc * 64;
        f32x4* orow = (f32x4*)(out + ((size_t)b * CC + c) * HWSZ);
#pragma unroll
        for (int i = 0; i < 4; ++i)
            __builtin_nontemporal_store(z, &orow[t + i * 256]);
    }
}

extern "C" void kernel_launch(void* const* d_in, const int* in_sizes, int n_in,
                              void* d_out, int out_size, void* d_ws, size_t ws_size,
                              hipStream_t stream) {
    const float* x  = (const float*)d_in[0];
    const float* W1 = (const float*)d_in[1];
    const float* W2 = (const float*)d_in[2];
    float* out = (float*)d_out;

    float* y = (float*)d_ws;                    // B*C floats

    mean_copy_kernel<<<BB * CC / 2, 256, 0, stream>>>(x, out, y);
    se_zero_kernel<<<BB * 64, 256, 0, stream>>>(y, W1, W2, out);
}